// Round 3
// baseline (113.966 us; speedup 1.0000x reference)
//
#include <hip/hip_runtime.h>
#include <hip/hip_bf16.h>

typedef __attribute__((ext_vector_type(4))) float f32x4;
typedef __attribute__((ext_vector_type(8))) short bf16x8;

#define NH 8
#define HD 64
#define WSZ 128
#define DM 512

__device__ __forceinline__ unsigned int pk2bf(float lo, float hi) {
    union { __hip_bfloat162 h; unsigned int u; } r;
    r.h = __float22bfloat162_rn(make_float2(lo, hi));
    return r.u;
}

__device__ __forceinline__ bf16x8 pack8(f32x4 a, f32x4 b) {
    union { unsigned int u[4]; bf16x8 v; } r;
    r.u[0] = pk2bf(a[0], a[1]);
    r.u[1] = pk2bf(a[2], a[3]);
    r.u[2] = pk2bf(b[0], b[1]);
    r.u[3] = pk2bf(b[2], b[3]);
    return r.v;
}

// One block = one (batch, window, head). 4 waves, each owns 32 query rows.
// LDS: Vt (16K) + Pl (10K) = 26.6K. K and Q are register-direct from global.
__global__ __launch_bounds__(256, 4) void wattn_kernel(
    const float* __restrict__ q1, const float* __restrict__ k1,
    const float* __restrict__ v1, float* __restrict__ o1, int nw1,
    const float* __restrict__ q2, const float* __restrict__ k2,
    const float* __restrict__ v2, float* __restrict__ o2, int nw2,
    int nblk1)
{
    // V^T tile bf16: Vt[d][k ^ (((d>>1)&7)<<3)] (XOR on aligned 8-blocks of k)
    __shared__ __align__(16) unsigned short Vt[64][128];
    // per-wave P chunk (32 q rows x 32 k), row padded to 40,
    // col swizzle: col ^ ((((row>>2)&3))<<3)
    __shared__ __align__(16) unsigned short Pl[4][32][40];

    const int t = threadIdx.x;
    const int lane = t & 63;
    const int wid = t >> 6;
    const int g = lane >> 4;    // 0..3
    const int c = lane & 15;    // 0..15

    int bid = blockIdx.x;
    const float *q, *k, *v; float* o; int nw;
    if (bid < nblk1) { q = q1; k = k1; v = v1; o = o1; nw = nw1; }
    else { bid -= nblk1; q = q2; k = k2; v = v2; o = o2; nw = nw2; }

    const int h = bid & (NH - 1);
    const int w = (bid / NH) % nw;
    const int b = bid / (NH * nw);

    const size_t row0 = ((size_t)b * nw + w) * WSZ;   // first token row of window
    const float* Qp = q + row0 * DM + h * HD;
    const float* Kp = k + row0 * DM + h * HD;
    const float* Vp = v + row0 * DM + h * HD;
    float* Op = o + row0 * DM + h * HD;

    // ---- issue V loads early (32 elems/thread of the 128x64 V tile) ----
    f32x4 vv[8];
#pragma unroll
    for (int i = 0; i < 8; ++i) {
        int e = (i * 256 + t) * 4;
        int kr = e >> 6, dc = e & 63;
        vv[i] = *reinterpret_cast<const f32x4*>(Vp + (size_t)kr * DM + dc);
    }

    // ---- issue Q loads (per-wave fragments) ----
    const int qrow0 = wid * 32;
    f32x4 qa[2][2], qb[2][2];
#pragma unroll
    for (int m = 0; m < 2; ++m)
#pragma unroll
        for (int ks = 0; ks < 2; ++ks) {
            const float* src = Qp + (size_t)(qrow0 + m * 16 + c) * DM + ks * 32 + g * 8;
            qa[m][ks] = *reinterpret_cast<const f32x4*>(src);
            qb[m][ks] = *reinterpret_cast<const f32x4*>(src + 4);
        }

    // ---- convert V + scatter into swizzled Vt (frees vv regs before QK^T) ----
#pragma unroll
    for (int i = 0; i < 8; ++i) {
        int e = (i * 256 + t) * 4;
        int kr = e >> 6, dc = e & 63;
#pragma unroll
        for (int j = 0; j < 4; ++j) {
            int d = dc + j;
            int xk = kr ^ (((d >> 1) & 7) << 3);
            union { __hip_bfloat16 h; unsigned short u; } cv;
            cv.h = __float2bfloat16(vv[i][j]);
            Vt[d][xk] = cv.u;
        }
    }

    // ---- convert Q ----
    bf16x8 qf[2][2];
#pragma unroll
    for (int m = 0; m < 2; ++m)
#pragma unroll
        for (int ks = 0; ks < 2; ++ks)
            qf[m][ks] = pack8(qa[m][ks], qb[m][ks]);

    // ---- S = Q K^T, K fragments register-direct from global (L1-served x4) ----
    f32x4 acc[2][8] = {};
#pragma unroll
    for (int ks = 0; ks < 2; ++ks) {
        bf16x8 kf[8];
#pragma unroll
        for (int n = 0; n < 8; ++n) {
            const float* src = Kp + (size_t)(n * 16 + c) * DM + ks * 32 + g * 8;
            f32x4 a = *reinterpret_cast<const f32x4*>(src);
            f32x4 bq = *reinterpret_cast<const f32x4*>(src + 4);
            kf[n] = pack8(a, bq);
        }
#pragma unroll
        for (int n = 0; n < 8; ++n) {
            acc[0][n] = __builtin_amdgcn_mfma_f32_16x16x32_bf16(qf[0][ks], kf[n], acc[0][n], 0, 0, 0);
            acc[1][n] = __builtin_amdgcn_mfma_f32_16x16x32_bf16(qf[1][ks], kf[n], acc[1][n], 0, 0, 0);
        }
    }

    // ---- softmax over k (cols); P left UNNORMALIZED, rinv applied at store ----
    const float CEXP = 0.125f * 1.4426950408889634f;   // scale * log2(e)
    float rinv[2][4];
#pragma unroll
    for (int m = 0; m < 2; ++m)
#pragma unroll
        for (int r = 0; r < 4; ++r) {
            float mx = acc[m][0][r];
#pragma unroll
            for (int n = 1; n < 8; ++n) mx = fmaxf(mx, acc[m][n][r]);
#pragma unroll
            for (int off = 1; off < 16; off <<= 1) mx = fmaxf(mx, __shfl_xor(mx, off));
            float s = 0.f;
#pragma unroll
            for (int n = 0; n < 8; ++n) {
                float p = exp2f((acc[m][n][r] - mx) * CEXP);
                acc[m][n][r] = p;
                s += p;
            }
#pragma unroll
            for (int off = 1; off < 16; off <<= 1) s += __shfl_xor(s, off);
            rinv[m][r] = 1.0f / s;
        }

    // Vt staging latency was hidden under QK^T + softmax; sync it now.
    __syncthreads();

    // ---- O = P V, k in 4 chunks of 32 through per-wave swizzled Pl ----
    f32x4 oacc[2][4] = {};
#pragma unroll
    for (int ck = 0; ck < 4; ++ck) {
#pragma unroll
        for (int m = 0; m < 2; ++m) {
            const int rowb = m * 16 + g * 4;
            const int cl0 = c ^ (g << 3);           // col 0..15 swizzled
            const int cl1 = (16 + c) ^ (g << 3);    // col 16..31 swizzled
#pragma unroll
            for (int r = 0; r < 4; ++r) {
                unsigned int pr = pk2bf(acc[m][ck * 2][r], acc[m][ck * 2 + 1][r]);
                Pl[wid][rowb + r][cl0] = (unsigned short)(pr & 0xffffu);
                Pl[wid][rowb + r][cl1] = (unsigned short)(pr >> 16);
            }
        }
        const int rb = (g ^ ((c >> 2) & 3)) * 8;
        bf16x8 pf0 = *reinterpret_cast<const bf16x8*>(&Pl[wid][c][rb]);
        bf16x8 pf1 = *reinterpret_cast<const bf16x8*>(&Pl[wid][16 + c][rb]);
#pragma unroll
        for (int n = 0; n < 4; ++n) {
            int d = n * 16 + c;
            int xk = (ck * 32 + g * 8) ^ (((d >> 1) & 7) << 3);
            bf16x8 vf = *reinterpret_cast<const bf16x8*>(&Vt[d][xk]);
            oacc[0][n] = __builtin_amdgcn_mfma_f32_16x16x32_bf16(pf0, vf, oacc[0][n], 0, 0, 0);
            oacc[1][n] = __builtin_amdgcn_mfma_f32_16x16x32_bf16(pf1, vf, oacc[1][n], 0, 0, 0);
        }
    }

    // ---- store O (fp32) with deferred 1/rowsum ----
#pragma unroll
    for (int m = 0; m < 2; ++m)
#pragma unroll
        for (int n = 0; n < 4; ++n)
#pragma unroll
            for (int r = 0; r < 4; ++r) {
                int row = qrow0 + m * 16 + g * 4 + r;
                Op[(size_t)row * DM + n * 16 + c] = oacc[m][n][r] * rinv[m][r];
            }
}

extern "C" void kernel_launch(void* const* d_in, const int* in_sizes, int n_in,
                              void* d_out, int out_size, void* d_ws, size_t ws_size,
                              hipStream_t stream) {
    const float* q1 = (const float*)d_in[0];
    const float* k1 = (const float*)d_in[1];
    const float* v1 = (const float*)d_in[2];
    const float* q2 = (const float*)d_in[3];
    const float* k2 = (const float*)d_in[4];
    const float* v2 = (const float*)d_in[5];

    // B=8 per the reference setup
    const int B = 8;
    const int nw1 = in_sizes[0] / (B * DM * WSZ);   // 32
    const int nw2 = in_sizes[3] / (B * DM * WSZ);   // 16

    float* o1 = (float*)d_out;
    float* o2 = o1 + (size_t)in_sizes[0];

    const int nblk1 = B * nw1 * NH;                 // 2048
    const int nblk2 = B * nw2 * NH;                 // 1024

    wattn_kernel<<<dim3(nblk1 + nblk2), dim3(256), 0, stream>>>(
        q1, k1, v1, o1, nw1, q2, k2, v2, o2, nw2, nblk1);
}

// Round 4
// 89.462 us; speedup vs baseline: 1.2739x; 1.2739x over previous
//
#include <hip/hip_runtime.h>
#include <hip/hip_bf16.h>

typedef __attribute__((ext_vector_type(4))) float f32x4;
typedef __attribute__((ext_vector_type(16))) float f32x16;
typedef __attribute__((ext_vector_type(8))) short bf16x8;

#define NH 8
#define HD 64
#define WSZ 128
#define DM 512

__device__ __forceinline__ unsigned int pk2bf(float lo, float hi) {
    union { __hip_bfloat162 h; unsigned int u; } r;
    r.h = __float22bfloat162_rn(make_float2(lo, hi));
    return r.u;
}

__device__ __forceinline__ bf16x8 pack8(f32x4 a, f32x4 b) {
    union { unsigned int u[4]; bf16x8 v; } r;
    r.u[0] = pk2bf(a[0], a[1]);
    r.u[1] = pk2bf(a[2], a[3]);
    r.u[2] = pk2bf(b[0], b[1]);
    r.u[3] = pk2bf(b[2], b[3]);
    return r.v;
}

// One block = one (batch, window, head). 4 waves, each owns 32 q-columns of S^T.
// 32x32x16 MFMA; swapped QK^T -> S^T so softmax is lane-local and P->PV goes
// through cvt_pk + v_permlane32_swap (no LDS for P). LDS: K 16K + Vt 16K = 32K.
__global__ __launch_bounds__(256, 4) void wattn_kernel(
    const float* __restrict__ q1, const float* __restrict__ k1,
    const float* __restrict__ v1, float* __restrict__ o1, int nw1,
    const float* __restrict__ q2, const float* __restrict__ k2,
    const float* __restrict__ v2, float* __restrict__ o2, int nw2,
    int nblk1)
{
    // K tile bf16 [128][64], swizzled: idx = row*64 + (col ^ ((row&7)<<3))
    __shared__ __align__(16) unsigned short Kl[128 * 64];
    // V^T tile bf16 [64][128], swizzled: idx = d*128 + (k ^ (((d>>1)&7)<<3))
    __shared__ __align__(16) unsigned short Vt[64 * 128];

    const int t = threadIdx.x;
    const int lane = t & 63;
    const int wid = t >> 6;
    const int hi = lane >> 5;   // 0..1
    const int c = lane & 31;    // 0..31

    int bid = blockIdx.x;
    const float *q, *k, *v; float* o; int nw;
    if (bid < nblk1) { q = q1; k = k1; v = v1; o = o1; nw = nw1; }
    else { bid -= nblk1; q = q2; k = k2; v = v2; o = o2; nw = nw2; }

    const int h = bid & (NH - 1);
    const int w = (bid / NH) % nw;
    const int b = bid / (NH * nw);

    const size_t row0 = ((size_t)b * nw + w) * WSZ;
    const float* Qp = q + row0 * DM + h * HD;
    const float* Kp = k + row0 * DM + h * HD;
    const float* Vp = v + row0 * DM + h * HD;
    float* Op = o + row0 * DM + h * HD;

    // ---- stage K: coalesced, conflict-free b128 writes ----
#pragma unroll
    for (int i = 0; i < 4; ++i) {
        int row = i * 32 + (t >> 3);
        int colf = (t & 7) * 8;
        const float* src = Kp + (size_t)row * DM + colf;
        f32x4 a = *reinterpret_cast<const f32x4*>(src);
        f32x4 bq = *reinterpret_cast<const f32x4*>(src + 4);
        union { unsigned int u[4]; } wv;
        wv.u[0] = pk2bf(a[0], a[1]);  wv.u[1] = pk2bf(a[2], a[3]);
        wv.u[2] = pk2bf(bq[0], bq[1]); wv.u[3] = pk2bf(bq[2], bq[3]);
        *reinterpret_cast<unsigned int*>(&Kl[row * 64 + (colf ^ ((row & 7) << 3))]) = wv.u[0];
        *reinterpret_cast<unsigned int*>(&Kl[row * 64 + ((colf + 2) ^ ((row & 7) << 3))]) = wv.u[1];
        *reinterpret_cast<unsigned int*>(&Kl[row * 64 + ((colf + 4) ^ ((row & 7) << 3))]) = wv.u[2];
        *reinterpret_cast<unsigned int*>(&Kl[row * 64 + ((colf + 6) ^ ((row & 7) << 3))]) = wv.u[3];
    }

    // ---- stage V transposed: paired-k b32 writes ----
#pragma unroll
    for (int i = 0; i < 4; ++i) {
        int rp = i * 16 + (t >> 4);          // row-pair: rows 2rp, 2rp+1
        int dc = (t & 15) * 4;
        f32x4 va = *reinterpret_cast<const f32x4*>(Vp + (size_t)(2 * rp) * DM + dc);
        f32x4 vb = *reinterpret_cast<const f32x4*>(Vp + (size_t)(2 * rp + 1) * DM + dc);
#pragma unroll
        for (int j = 0; j < 4; ++j) {
            int d = dc + j;
            int idx = d * 128 + ((2 * rp) ^ (((d >> 1) & 7) << 3));   // even
            *reinterpret_cast<unsigned int*>(&Vt[idx]) = pk2bf(va[j], vb[j]);
        }
    }

    // ---- Q fragments direct from global (B-operand: q=qbase+c, d=ks*16+hi*8+j) ----
    const int qbase = wid * 32;
    bf16x8 qf[4];
#pragma unroll
    for (int ks = 0; ks < 4; ++ks) {
        const float* src = Qp + (size_t)(qbase + c) * DM + ks * 16 + hi * 8;
        f32x4 a = *reinterpret_cast<const f32x4*>(src);
        f32x4 bq = *reinterpret_cast<const f32x4*>(src + 4);
        qf[ks] = pack8(a, bq);
    }

    __syncthreads();

    // ---- S^T = K Q^T : acc[mf], D: col=c (q), row k = mf*32+(reg&3)+8*(reg>>2)+4*hi
    f32x16 acc[4] = {};
#pragma unroll
    for (int ks = 0; ks < 4; ++ks) {
#pragma unroll
        for (int mf = 0; mf < 4; ++mf) {
            const bf16x8 kf = *reinterpret_cast<const bf16x8*>(
                &Kl[(mf * 32 + c) * 64 + ((ks * 16 + hi * 8) ^ ((c & 7) << 3))]);
            acc[mf] = __builtin_amdgcn_mfma_f32_32x32x16_bf16(kf, qf[ks], acc[mf], 0, 0, 0);
        }
    }

    // ---- softmax over k: 64 lane-local + 1 cross-half reduce ----
    const float CEXP = 0.125f * 1.4426950408889634f;
    float mx = acc[0][0];
#pragma unroll
    for (int f = 0; f < 4; ++f)
#pragma unroll
        for (int e = 0; e < 16; ++e) mx = fmaxf(mx, acc[f][e]);
    mx = fmaxf(mx, __shfl_xor(mx, 32));
    const float mxc = mx * CEXP;
    float sum = 0.f;
#pragma unroll
    for (int f = 0; f < 4; ++f)
#pragma unroll
        for (int e = 0; e < 16; ++e) {
            float p = exp2f(acc[f][e] * CEXP - mxc);
            acc[f][e] = p;
            sum += p;
        }
    sum += __shfl_xor(sum, 32);
    const float rinv = 1.0f / sum;

    // ---- O = P V : per 16-k block, pack P + permlane32_swap -> A-frag in regs ----
    f32x16 oacc[2] = {};
#pragma unroll
    for (int f = 0; f < 4; ++f) {
#pragma unroll
        for (int p = 0; p < 2; ++p) {
            const int kb = f * 2 + p;
            unsigned int U0 = pk2bf(acc[f][8 * p + 0], acc[f][8 * p + 1]);
            unsigned int U1 = pk2bf(acc[f][8 * p + 2], acc[f][8 * p + 3]);
            unsigned int U2 = pk2bf(acc[f][8 * p + 4], acc[f][8 * p + 5]);
            unsigned int U3 = pk2bf(acc[f][8 * p + 6], acc[f][8 * p + 7]);
            // swap upper lanes of U0 with lower lanes of U2 (and U1<->U3):
            // result: U0..U3 become the A-frag words k = kb*16+hi*8+{0..7}
            asm volatile("v_permlane32_swap_b32 %0, %1" : "+v"(U0), "+v"(U2));
            asm volatile("v_permlane32_swap_b32 %0, %1" : "+v"(U1), "+v"(U3));
            union { unsigned int u[4]; bf16x8 v; } A;
            A.u[0] = U0; A.u[1] = U1; A.u[2] = U2; A.u[3] = U3;
#pragma unroll
            for (int nf = 0; nf < 2; ++nf) {
                const int d = nf * 32 + c;
                const bf16x8 vf = *reinterpret_cast<const bf16x8*>(
                    &Vt[d * 128 + ((kb * 16 + hi * 8) ^ (((d >> 1) & 7) << 3))]);
                oacc[nf] = __builtin_amdgcn_mfma_f32_32x32x16_bf16(A.v, vf, oacc[nf], 0, 0, 0);
            }
        }
    }

    // ---- store O with deferred 1/rowsum broadcast from q-owner lanes ----
#pragma unroll
    for (int reg = 0; reg < 16; ++reg) {
        const int qr = (reg & 3) + 8 * (reg >> 2) + 4 * hi;
        const float rv = __shfl(rinv, qr);   // rinv for q-col qr lives at lane qr (both halves)
#pragma unroll
        for (int nf = 0; nf < 2; ++nf) {
            Op[(size_t)(qbase + qr) * DM + nf * 32 + c] = oacc[nf][reg] * rv;
        }
    }
}

extern "C" void kernel_launch(void* const* d_in, const int* in_sizes, int n_in,
                              void* d_out, int out_size, void* d_ws, size_t ws_size,
                              hipStream_t stream) {
    const float* q1 = (const float*)d_in[0];
    const float* k1 = (const float*)d_in[1];
    const float* v1 = (const float*)d_in[2];
    const float* q2 = (const float*)d_in[3];
    const float* k2 = (const float*)d_in[4];
    const float* v2 = (const float*)d_in[5];

    const int B = 8;
    const int nw1 = in_sizes[0] / (B * DM * WSZ);   // 32
    const int nw2 = in_sizes[3] / (B * DM * WSZ);   // 16

    float* o1 = (float*)d_out;
    float* o2 = o1 + (size_t)in_sizes[0];

    const int nblk1 = B * nw1 * NH;                 // 2048
    const int nblk2 = B * nw2 * NH;                 // 1024

    wattn_kernel<<<dim3(nblk1 + nblk2), dim3(256), 0, stream>>>(
        q1, k1, v1, o1, nw1, q2, k2, v2, o2, nw2, nblk1);
}